// Round 1
// baseline (1642.083 us; speedup 1.0000x reference)
//
#include <hip/hip_runtime.h>

// RegionAttention fp32 baseline.
// L=16384 -> Hs=Ws=128, r=32 -> 16 regions x 1024 tokens. HEADS=8, HD=64.
// ws layout (fp32): q[16][8][1024][64], k[...], v[...], ao[16384][512]  (134.2 MB)

#define SCALE 0.125f

__device__ __forceinline__ int l_from_rn(int region, int n) {
    // region = gi*4+gj (gi,gj in [0,4)); n = a*32+b (a,b in [0,32))
    int gi = region >> 2, gj = region & 3;
    int a = n >> 5, b = n & 31;
    return ((gi * 32 + a) << 7) + (gj << 5) + b;   // l = h*128 + w
}

// ---------------- Kernel 1: QKV GEMM ----------------
// C[t][c] = sum_k x[l(t)][k] * qkv_w[c][k] + qkv_b[c]
// scatter: c -> (s,h,d); write (q|k|v)[(region*8+h)*1024+n][d]
__global__ __launch_bounds__(256) void qkv_kernel(
    const float* __restrict__ x, const float* __restrict__ w,
    const float* __restrict__ bias, float* __restrict__ q,
    float* __restrict__ k, float* __restrict__ v)
{
    __shared__ float Xs[64][36];
    __shared__ float Ws[64][36];
    const int c0 = blockIdx.x * 64;   // 0..1535
    const int t0 = blockIdx.y * 64;   // 0..16383
    const int tid = threadIdx.x;
    const int tc = tid & 15, tr = tid >> 4;
    float acc[4][4] = {};
    for (int k0 = 0; k0 < 512; k0 += 32) {
        for (int i = tid; i < 512; i += 256) {
            int row = i >> 3, kq = i & 7;
            int t = t0 + row;
            int l = l_from_rn(t >> 10, t & 1023);
            *(float4*)(&Xs[row][kq * 4]) =
                *(const float4*)(x + (size_t)l * 512 + k0 + kq * 4);
        }
        for (int i = tid; i < 512; i += 256) {
            int row = i >> 3, kq = i & 7;
            *(float4*)(&Ws[row][kq * 4]) =
                *(const float4*)(w + (size_t)(c0 + row) * 512 + k0 + kq * 4);
        }
        __syncthreads();
        #pragma unroll
        for (int kk = 0; kk < 32; ++kk) {
            float a4[4], b4[4];
            #pragma unroll
            for (int i = 0; i < 4; ++i) a4[i] = Xs[tr * 4 + i][kk];
            #pragma unroll
            for (int j = 0; j < 4; ++j) b4[j] = Ws[tc * 4 + j][kk];
            #pragma unroll
            for (int i = 0; i < 4; ++i)
                #pragma unroll
                for (int j = 0; j < 4; ++j)
                    acc[i][j] += a4[i] * b4[j];
        }
        __syncthreads();
    }
    // col tile (64 wide) lies inside one (s, h): s = c0/512, h = (c0%512)/64
    const int s = c0 >> 9;
    const int h = (c0 & 511) >> 6;
    float* dst = (s == 0) ? q : (s == 1) ? k : v;
    #pragma unroll
    for (int i = 0; i < 4; ++i) {
        int t = t0 + tr * 4 + i;
        int region = t >> 10, n = t & 1023;
        float* drow = dst + ((size_t)(region * 8 + h) * 1024 + n) * 64;
        #pragma unroll
        for (int j = 0; j < 4; ++j) {
            int c = c0 + tc * 4 + j;
            drow[c & 63] = acc[i][j] + bias[c];
        }
    }
}

// ---------------- Kernel 2: attention with fused EPEG conv + softmax ----------------
// One block per (region, head, 64-row block). Flash-style over 16 j-tiles of 64.
// S rows staged for [i0-2, i0+66) so the 5-tap conv along i has its halo.
__global__ __launch_bounds__(256) void attn_kernel(
    const float* __restrict__ q, const float* __restrict__ k,
    const float* __restrict__ v, const float* __restrict__ epw,
    const float* __restrict__ epb, float* __restrict__ ao)
{
    const int rb = blockIdx.x;      // 0..15
    const int head = blockIdx.y;    // 0..7
    const int region = blockIdx.z;  // 0..15
    const int rh = region * 8 + head;
    const float* qb = q + (size_t)rh * 1024 * 64;
    const float* kb = k + (size_t)rh * 1024 * 64;
    const float* vb = v + (size_t)rh * 1024 * 64;
    const int i0 = rb * 64;
    const int tid = threadIdx.x;

    __shared__ float Qs[68][68];    // rows i0-2 .. i0+65 (OOB rows zeroed)
    __shared__ float Ks[64][68];
    __shared__ float Vs[64][68];
    __shared__ float Ss[68][68];    // raw scaled logits; rows 0..63 reused as P
    __shared__ float row_scale[64];
    __shared__ float row_l[64];

    for (int i = tid; i < 68 * 16; i += 256) {
        int ih = i >> 4, dq = i & 15;
        int gi = i0 - 2 + ih;
        float4 val = make_float4(0.f, 0.f, 0.f, 0.f);
        if (gi >= 0 && gi < 1024)
            val = *(const float4*)(qb + (size_t)gi * 64 + dq * 4);
        *(float4*)(&Qs[ih][dq * 4]) = val;
    }

    float cw[5];
    #pragma unroll
    for (int t = 0; t < 5; ++t) cw[t] = epw[head * 5 + t];
    const float cb = epb[head];

    float m_r = -1e30f, l_r = 0.f;
    const int rgrp = tid >> 4, dg = tid & 15;   // PV: 4 rows x 4 d per thread
    float acc[4][4] = {};

    for (int jt = 0; jt < 16; ++jt) {
        const int j0 = jt * 64;
        __syncthreads();   // previous-tile PV done (and Q load for jt==0)
        for (int i = tid; i < 64 * 16; i += 256) {
            int jj = i >> 4, dq = i & 15;
            *(float4*)(&Ks[jj][dq * 4]) =
                *(const float4*)(kb + (size_t)(j0 + jj) * 64 + dq * 4);
            *(float4*)(&Vs[jj][dq * 4]) =
                *(const float4*)(vb + (size_t)(j0 + jj) * 64 + dq * 4);
        }
        __syncthreads();

        // S = scale * Q K^T : rows 0..63 via 4x4 micro, halo rows 64..67
        {
            const int stc = tid & 15, str = tid >> 4;
            float sacc[4][4] = {};
            for (int d = 0; d < 64; ++d) {
                float a4[4], b4[4];
                #pragma unroll
                for (int i2 = 0; i2 < 4; ++i2) a4[i2] = Qs[str * 4 + i2][d];
                #pragma unroll
                for (int j2 = 0; j2 < 4; ++j2) b4[j2] = Ks[stc * 4 + j2][d];
                #pragma unroll
                for (int i2 = 0; i2 < 4; ++i2)
                    #pragma unroll
                    for (int j2 = 0; j2 < 4; ++j2)
                        sacc[i2][j2] += a4[i2] * b4[j2];
            }
            #pragma unroll
            for (int i2 = 0; i2 < 4; ++i2)
                #pragma unroll
                for (int j2 = 0; j2 < 4; ++j2)
                    Ss[str * 4 + i2][stc * 4 + j2] = sacc[i2][j2] * SCALE;
            int ih = 64 + (tid >> 6);
            int jj = tid & 63;
            float sdot = 0.f;
            for (int d = 0; d < 64; ++d) sdot += Qs[ih][d] * Ks[jj][d];
            Ss[ih][jj] = sdot * SCALE;
        }
        __syncthreads();

        // softmax phase A (threads 0..63, one row each): conv + online stats, s~ in regs
        float st[64];
        if (tid < 64) {
            const int r = tid;
            float mx = -1e30f;
            #pragma unroll
            for (int j = 0; j < 64; ++j) {
                float sv = cb + Ss[r + 2][j];
                #pragma unroll
                for (int t = 0; t < 5; ++t) sv += cw[t] * Ss[r + t][j];
                st[j] = sv;
                mx = fmaxf(mx, sv);
            }
            float mnew = fmaxf(m_r, mx);
            float sc = __expf(m_r - mnew);
            float ssum = 0.f;
            #pragma unroll
            for (int j = 0; j < 64; ++j) {
                float p = __expf(st[j] - mnew);
                st[j] = p;
                ssum += p;
            }
            m_r = mnew;
            l_r = l_r * sc + ssum;
            row_scale[r] = sc;
        }
        __syncthreads();
        // phase B: P overwrites Ss rows 0..63 (all reads of Sraw are done)
        if (tid < 64) {
            #pragma unroll
            for (int j = 0; j < 16; ++j)
                *(float4*)(&Ss[tid][j * 4]) = *(float4*)(&st[j * 4]);
        }
        __syncthreads();

        // PV: acc = acc*row_scale + P @ V
        #pragma unroll
        for (int rr = 0; rr < 4; ++rr) {
            float sc = row_scale[rgrp * 4 + rr];
            #pragma unroll
            for (int dd = 0; dd < 4; ++dd) acc[rr][dd] *= sc;
        }
        for (int j = 0; j < 64; ++j) {
            float p4[4], v4[4];
            #pragma unroll
            for (int rr = 0; rr < 4; ++rr) p4[rr] = Ss[rgrp * 4 + rr][j];
            #pragma unroll
            for (int dd = 0; dd < 4; ++dd) v4[dd] = Vs[j][dg * 4 + dd];
            #pragma unroll
            for (int rr = 0; rr < 4; ++rr)
                #pragma unroll
                for (int dd = 0; dd < 4; ++dd)
                    acc[rr][dd] += p4[rr] * v4[dd];
        }
    }

    if (tid < 64) row_l[tid] = l_r;
    __syncthreads();
    #pragma unroll
    for (int rr = 0; rr < 4; ++rr) {
        int r = rgrp * 4 + rr;
        float inv = 1.f / row_l[r];
        size_t t = (size_t)region * 1024 + i0 + r;
        float* orow = ao + t * 512 + head * 64 + dg * 4;
        #pragma unroll
        for (int dd = 0; dd < 4; ++dd) orow[dd] = acc[rr][dd] * inv;
    }
}

// ---------------- Kernel 3: proj GEMM ----------------
// out[l(t)][c] = sum_k ao[t][k] * proj_w[c][k] + proj_b[c]
__global__ __launch_bounds__(256) void proj_kernel(
    const float* __restrict__ ao, const float* __restrict__ w,
    const float* __restrict__ bias, float* __restrict__ out)
{
    __shared__ float As[64][36];
    __shared__ float Bs[64][36];
    const int c0 = blockIdx.x * 64;   // 0..511
    const int t0 = blockIdx.y * 64;
    const int tid = threadIdx.x;
    const int tc = tid & 15, tr = tid >> 4;
    float acc[4][4] = {};
    for (int k0 = 0; k0 < 512; k0 += 32) {
        for (int i = tid; i < 512; i += 256) {
            int row = i >> 3, kq = i & 7;
            *(float4*)(&As[row][kq * 4]) =
                *(const float4*)(ao + (size_t)(t0 + row) * 512 + k0 + kq * 4);
            *(float4*)(&Bs[row][kq * 4]) =
                *(const float4*)(w + (size_t)(c0 + row) * 512 + k0 + kq * 4);
        }
        __syncthreads();
        #pragma unroll
        for (int kk = 0; kk < 32; ++kk) {
            float a4[4], b4[4];
            #pragma unroll
            for (int i = 0; i < 4; ++i) a4[i] = As[tr * 4 + i][kk];
            #pragma unroll
            for (int j = 0; j < 4; ++j) b4[j] = Bs[tc * 4 + j][kk];
            #pragma unroll
            for (int i = 0; i < 4; ++i)
                #pragma unroll
                for (int j = 0; j < 4; ++j)
                    acc[i][j] += a4[i] * b4[j];
        }
        __syncthreads();
    }
    #pragma unroll
    for (int i = 0; i < 4; ++i) {
        int t = t0 + tr * 4 + i;
        int l = l_from_rn(t >> 10, t & 1023);
        #pragma unroll
        for (int j = 0; j < 4; ++j) {
            int c = c0 + tc * 4 + j;
            out[(size_t)l * 512 + c] = acc[i][j] + bias[c];
        }
    }
}

extern "C" void kernel_launch(void* const* d_in, const int* in_sizes, int n_in,
                              void* d_out, int out_size, void* d_ws, size_t ws_size,
                              hipStream_t stream) {
    const float* x      = (const float*)d_in[0];
    const float* qkv_w  = (const float*)d_in[1];
    const float* qkv_b  = (const float*)d_in[2];
    const float* proj_w = (const float*)d_in[3];
    const float* proj_b = (const float*)d_in[4];
    const float* epeg_w = (const float*)d_in[5];
    const float* epeg_b = (const float*)d_in[6];
    float* out = (float*)d_out;

    const size_t NQKV = (size_t)16 * 8 * 1024 * 64;   // 8388608
    float* q  = (float*)d_ws;
    float* k  = q + NQKV;
    float* v  = k + NQKV;
    float* ao = v + NQKV;   // [16384][512]

    {
        dim3 grid(24, 256);   // 1536/64 cols x 16384/64 rows
        qkv_kernel<<<grid, 256, 0, stream>>>(x, qkv_w, qkv_b, q, k, v);
    }
    {
        dim3 grid(16, 8, 16); // row-blocks x heads x regions
        attn_kernel<<<grid, 256, 0, stream>>>(q, k, v, epeg_w, epeg_b, ao);
    }
    {
        dim3 grid(8, 256);    // 512/64 cols x 16384/64 rows
        proj_kernel<<<grid, 256, 0, stream>>>(ao, proj_w, proj_b, out);
    }
}

// Round 2
// 1335.260 us; speedup vs baseline: 1.2298x; 1.2298x over previous
//
#include <hip/hip_runtime.h>

// RegionAttention: fp32 GEMMs + bf16-MFMA attention.
// L=16384 -> 16 regions x 1024 tokens. HEADS=8, HD=64.
// ws (bytes): q bf16[16MB] | k bf16[16MB] | vT bf16[16MB] | ao fp32[32MB]

#define SCALE 0.125f

using bf16x8 = __attribute__((ext_vector_type(8))) short;
using f32x4  = __attribute__((ext_vector_type(4))) float;

__device__ __forceinline__ unsigned short f2bf(float f) {
    unsigned u = __float_as_uint(f);
    u += 0x7fff + ((u >> 16) & 1);
    return (unsigned short)(u >> 16);
}
__device__ __forceinline__ float bf2f(unsigned short s) {
    return __uint_as_float(((unsigned)s) << 16);
}
__device__ __forceinline__ void gload16(const void* g, void* l) {
    __builtin_amdgcn_global_load_lds(
        (const __attribute__((address_space(1))) void*)g,
        (__attribute__((address_space(3))) void*)l, 16, 0, 0);
}

__device__ __forceinline__ int l_from_rn(int region, int n) {
    int gi = region >> 2, gj = region & 3;
    int a = n >> 5, b = n & 31;
    return ((gi * 32 + a) << 7) + (gj << 5) + b;
}

// ---------------- Kernel 1: QKV GEMM (fp32 compute, bf16 out; v transposed) ---------
__global__ __launch_bounds__(256) void qkv_kernel(
    const float* __restrict__ x, const float* __restrict__ w,
    const float* __restrict__ bias, unsigned short* __restrict__ qo,
    unsigned short* __restrict__ ko, unsigned short* __restrict__ vto)
{
    __shared__ float Xs[64][36];
    __shared__ float Ws[64][36];
    const int c0 = blockIdx.x * 64;
    const int t0 = blockIdx.y * 64;
    const int tid = threadIdx.x;
    const int tc = tid & 15, tr = tid >> 4;
    float acc[4][4] = {};
    for (int k0 = 0; k0 < 512; k0 += 32) {
        for (int i = tid; i < 512; i += 256) {
            int row = i >> 3, kq = i & 7;
            int t = t0 + row;
            int l = l_from_rn(t >> 10, t & 1023);
            *(float4*)(&Xs[row][kq * 4]) =
                *(const float4*)(x + (size_t)l * 512 + k0 + kq * 4);
        }
        for (int i = tid; i < 512; i += 256) {
            int row = i >> 3, kq = i & 7;
            *(float4*)(&Ws[row][kq * 4]) =
                *(const float4*)(w + (size_t)(c0 + row) * 512 + k0 + kq * 4);
        }
        __syncthreads();
        #pragma unroll
        for (int kk = 0; kk < 32; ++kk) {
            float a4[4], b4[4];
            #pragma unroll
            for (int i = 0; i < 4; ++i) a4[i] = Xs[tr * 4 + i][kk];
            #pragma unroll
            for (int j = 0; j < 4; ++j) b4[j] = Ws[tc * 4 + j][kk];
            #pragma unroll
            for (int i = 0; i < 4; ++i)
                #pragma unroll
                for (int j = 0; j < 4; ++j)
                    acc[i][j] += a4[i] * b4[j];
        }
        __syncthreads();
    }
    const int s = c0 >> 9;
    const int h = (c0 & 511) >> 6;
    if (s < 2) {
        unsigned short* dst = (s == 0) ? qo : ko;
        #pragma unroll
        for (int i = 0; i < 4; ++i) {
            int t = t0 + tr * 4 + i;
            int region = t >> 10, n = t & 1023;
            unsigned short* drow =
                dst + ((size_t)(region * 8 + h) * 1024 + n) * 64 + tc * 4;
            ushort4 pk;
            pk.x = f2bf(acc[i][0] + bias[c0 + tc * 4 + 0]);
            pk.y = f2bf(acc[i][1] + bias[c0 + tc * 4 + 1]);
            pk.z = f2bf(acc[i][2] + bias[c0 + tc * 4 + 2]);
            pk.w = f2bf(acc[i][3] + bias[c0 + tc * 4 + 3]);
            *(ushort4*)drow = pk;
        }
    } else {
        int t = t0 + tr * 4;
        int region = t >> 10;
        int n0 = t & 1023;
        unsigned short* base = vto + (size_t)(region * 8 + h) * 65536;
        #pragma unroll
        for (int j = 0; j < 4; ++j) {
            int d = tc * 4 + j;
            float b = bias[c0 + d];
            ushort4 pk;
            pk.x = f2bf(acc[0][j] + b);
            pk.y = f2bf(acc[1][j] + b);
            pk.z = f2bf(acc[2][j] + b);
            pk.w = f2bf(acc[3][j] + b);
            *(ushort4*)(base + (size_t)d * 1024 + n0) = pk;
        }
    }
}

// ---------------- Kernel 2: bf16 MFMA attention + fused EPEG conv/softmax ----------
__global__ __launch_bounds__(256) void attn_kernel(
    const unsigned short* __restrict__ qg, const unsigned short* __restrict__ kg,
    const unsigned short* __restrict__ vtg, const float* __restrict__ epw,
    const float* __restrict__ epb, float* __restrict__ ao)
{
    const int rb = blockIdx.x, head = blockIdx.y, region = blockIdx.z;
    const int rh = region * 8 + head;
    const unsigned short* qb = qg + (size_t)rh * 65536;
    const unsigned short* kb = kg + (size_t)rh * 65536;
    const unsigned short* vb = vtg + (size_t)rh * 65536;
    const int i0 = rb * 64;
    const int tid = threadIdx.x;
    const int lane = tid & 63, w = tid >> 6;
    const int arow = lane & 15, kgrp = lane >> 4;

    __shared__ __align__(16) unsigned short Ks[64 * 64];
    __shared__ __align__(16) unsigned short VTs[64 * 64];
    __shared__ __align__(16) unsigned short Ps[64 * 64];
    __shared__ __align__(16) float Ss[68][68];
    __shared__ __align__(16) unsigned short Qh[4 * 64];
    __shared__ float row_scale[64];
    __shared__ float row_l[64];

    // Q fragments in registers (reused across all 16 j-tiles)
    bf16x8 qf0, qf1;
    {
        const unsigned short* p = qb + (size_t)(i0 + w * 16 + arow) * 64 + kgrp * 8;
        qf0 = *(const bf16x8*)p;
        qf1 = *(const bf16x8*)(p + 32);
    }
    // halo Q rows i0-2,i0-1,i0+64,i0+65 (zero outside [0,1024) == conv zero-pad)
    if (tid < 32) {
        int hr = tid >> 3, c8 = tid & 7;
        int gi = (hr < 2) ? (i0 - 2 + hr) : (i0 + 62 + hr);
        bf16x8 val;
        #pragma unroll
        for (int e = 0; e < 8; ++e) val[e] = 0;
        if (gi >= 0 && gi < 1024)
            val = *(const bf16x8*)(qb + (size_t)gi * 64 + c8 * 8);
        *(bf16x8*)&Qh[hr * 64 + c8 * 8] = val;
    }

    float cw[5];
    #pragma unroll
    for (int t = 0; t < 5; ++t) cw[t] = epw[head * 5 + t];
    const float cb = epb[head];

    const int srow = tid >> 2, scol = tid & 3;
    float m_r = -1e30f, l_r = 0.f;
    f32x4 oacc[4];
    #pragma unroll
    for (int dt = 0; dt < 4; ++dt) {
        f32x4 z = {0.f, 0.f, 0.f, 0.f};
        oacc[dt] = z;
    }

    for (int jt = 0; jt < 16; ++jt) {
        const int j0 = jt * 64;
        __syncthreads();   // prev PV reads of Ks/VTs done (jt=0: Qh written)
        // stage K and VT: linear LDS dest, inverse-swizzled global source
        #pragma unroll
        for (int it = 0; it < 2; ++it) {
            int q = (it * 4 + w) * 64 + lane;
            int row = q >> 3, phys = q & 7, c8 = phys ^ (row & 7);
            gload16(kb + (size_t)(j0 + row) * 64 + c8 * 8, &Ks[(it * 4 + w) * 512]);
            gload16(vb + (size_t)row * 1024 + j0 + c8 * 8, &VTs[(it * 4 + w) * 512]);
        }
        __syncthreads();   // staging complete (barrier drains vmcnt)

        // S = scale * Q K^T via MFMA; wave w owns rows i0+w*16..+16
        #pragma unroll
        for (int ct = 0; ct < 4; ++ct) {
            f32x4 sacc = {0.f, 0.f, 0.f, 0.f};
            int krow = ct * 16 + arow;
            int ph0 = kgrp ^ (krow & 7);
            int ph1 = (4 + kgrp) ^ (krow & 7);
            bf16x8 kf0 = *(const bf16x8*)&Ks[krow * 64 + ph0 * 8];
            bf16x8 kf1 = *(const bf16x8*)&Ks[krow * 64 + ph1 * 8];
            sacc = __builtin_amdgcn_mfma_f32_16x16x32_bf16(qf0, kf0, sacc, 0, 0, 0);
            sacc = __builtin_amdgcn_mfma_f32_16x16x32_bf16(qf1, kf1, sacc, 0, 0, 0);
            int sc_ = ct * 16 + arow;
            int sr = 2 + w * 16 + kgrp * 4;
            #pragma unroll
            for (int i = 0; i < 4; ++i) Ss[sr + i][sc_] = sacc[i] * SCALE;
        }
        // 4 halo rows (VALU): wave w computes one halo row across 64 cols
        {
            int hr = w, hc = lane;
            float dot = 0.f;
            #pragma unroll
            for (int c8 = 0; c8 < 8; ++c8) {
                bf16x8 qv = *(const bf16x8*)&Qh[hr * 64 + c8 * 8];
                int ph = c8 ^ (hc & 7);
                bf16x8 kv = *(const bf16x8*)&Ks[hc * 64 + ph * 8];
                #pragma unroll
                for (int e = 0; e < 8; ++e)
                    dot += bf2f((unsigned short)qv[e]) * bf2f((unsigned short)kv[e]);
            }
            int hsr = (hr < 2) ? hr : hr + 64;   // Ss rows 0,1,66,67
            Ss[hsr][hc] = dot * SCALE;
        }
        __syncthreads();   // S tile + halo complete

        // conv + online softmax: 4 threads per row, 16 cols each
        float st[16];
        float mx = -1e30f;
        {
            int r = srow, cb0 = scol * 16;
            #pragma unroll
            for (int cc = 0; cc < 4; ++cc) {
                float4 a0 = *(const float4*)&Ss[r + 0][cb0 + cc * 4];
                float4 a1 = *(const float4*)&Ss[r + 1][cb0 + cc * 4];
                float4 a2 = *(const float4*)&Ss[r + 2][cb0 + cc * 4];
                float4 a3 = *(const float4*)&Ss[r + 3][cb0 + cc * 4];
                float4 a4 = *(const float4*)&Ss[r + 4][cb0 + cc * 4];
                float v0 = a2.x + cb + cw[0]*a0.x + cw[1]*a1.x + cw[2]*a2.x + cw[3]*a3.x + cw[4]*a4.x;
                float v1 = a2.y + cb + cw[0]*a0.y + cw[1]*a1.y + cw[2]*a2.y + cw[3]*a3.y + cw[4]*a4.y;
                float v2 = a2.z + cb + cw[0]*a0.z + cw[1]*a1.z + cw[2]*a2.z + cw[3]*a3.z + cw[4]*a4.z;
                float v3 = a2.w + cb + cw[0]*a0.w + cw[1]*a1.w + cw[2]*a2.w + cw[3]*a3.w + cw[4]*a4.w;
                st[cc * 4 + 0] = v0; st[cc * 4 + 1] = v1;
                st[cc * 4 + 2] = v2; st[cc * 4 + 3] = v3;
                mx = fmaxf(mx, fmaxf(fmaxf(v0, v1), fmaxf(v2, v3)));
            }
        }
        mx = fmaxf(mx, __shfl_xor(mx, 1));
        mx = fmaxf(mx, __shfl_xor(mx, 2));
        float mnew = fmaxf(m_r, mx);
        float scl = __expf(m_r - mnew);
        float ssum = 0.f;
        #pragma unroll
        for (int j = 0; j < 16; ++j) {
            st[j] = __expf(st[j] - mnew);
            ssum += st[j];
        }
        ssum += __shfl_xor(ssum, 1);
        ssum += __shfl_xor(ssum, 2);
        m_r = mnew;
        l_r = l_r * scl + ssum;
        if (scol == 0) row_scale[srow] = scl;

        // P -> bf16 LDS (wave-local; swizzled like Ks)
        {
            int r = srow;
            #pragma unroll
            for (int e = 0; e < 2; ++e) {
                bf16x8 pk;
                #pragma unroll
                for (int e2 = 0; e2 < 8; ++e2)
                    pk[e2] = (short)f2bf(st[e * 8 + e2]);
                int ch = scol * 2 + e;
                *(bf16x8*)&Ps[r * 64 + ((ch ^ (r & 7)) * 8)] = pk;
            }
        }
        // PV MFMA (all wave-local LDS reads; DS ops are in-order per wave)
        {
            int prow = w * 16 + arow;
            int pp0 = kgrp ^ (prow & 7);
            int pp1 = (4 + kgrp) ^ (prow & 7);
            bf16x8 pf0 = *(const bf16x8*)&Ps[prow * 64 + pp0 * 8];
            bf16x8 pf1 = *(const bf16x8*)&Ps[prow * 64 + pp1 * 8];
            float rs[4];
            #pragma unroll
            for (int i = 0; i < 4; ++i) rs[i] = row_scale[w * 16 + kgrp * 4 + i];
            #pragma unroll
            for (int dt = 0; dt < 4; ++dt) {
                int drow = dt * 16 + arow;
                int vp0 = kgrp ^ (drow & 7);
                int vp1 = (4 + kgrp) ^ (drow & 7);
                bf16x8 vf0 = *(const bf16x8*)&VTs[drow * 64 + vp0 * 8];
                bf16x8 vf1 = *(const bf16x8*)&VTs[drow * 64 + vp1 * 8];
                f32x4 t = oacc[dt];
                #pragma unroll
                for (int i = 0; i < 4; ++i) t[i] *= rs[i];
                t = __builtin_amdgcn_mfma_f32_16x16x32_bf16(pf0, vf0, t, 0, 0, 0);
                t = __builtin_amdgcn_mfma_f32_16x16x32_bf16(pf1, vf1, t, 0, 0, 0);
                oacc[dt] = t;
            }
        }
    }

    if (scol == 0) row_l[srow] = l_r;
    __syncthreads();
    float inv[4];
    #pragma unroll
    for (int i = 0; i < 4; ++i) inv[i] = 1.f / row_l[w * 16 + kgrp * 4 + i];
    #pragma unroll
    for (int dt = 0; dt < 4; ++dt) {
        #pragma unroll
        for (int i = 0; i < 4; ++i) {
            size_t t = (size_t)region * 1024 + i0 + w * 16 + kgrp * 4 + i;
            ao[t * 512 + head * 64 + dt * 16 + arow] = oacc[dt][i] * inv[i];
        }
    }
}

// ---------------- Kernel 3: proj GEMM (fp32) ----------------
__global__ __launch_bounds__(256) void proj_kernel(
    const float* __restrict__ ao, const float* __restrict__ w,
    const float* __restrict__ bias, float* __restrict__ out)
{
    __shared__ float As[64][36];
    __shared__ float Bs[64][36];
    const int c0 = blockIdx.x * 64;
    const int t0 = blockIdx.y * 64;
    const int tid = threadIdx.x;
    const int tc = tid & 15, tr = tid >> 4;
    float acc[4][4] = {};
    for (int k0 = 0; k0 < 512; k0 += 32) {
        for (int i = tid; i < 512; i += 256) {
            int row = i >> 3, kq = i & 7;
            *(float4*)(&As[row][kq * 4]) =
                *(const float4*)(ao + (size_t)(t0 + row) * 512 + k0 + kq * 4);
            *(float4*)(&Bs[row][kq * 4]) =
                *(const float4*)(w + (size_t)(c0 + row) * 512 + k0 + kq * 4);
        }
        __syncthreads();
        #pragma unroll
        for (int kk = 0; kk < 32; ++kk) {
            float a4[4], b4[4];
            #pragma unroll
            for (int i = 0; i < 4; ++i) a4[i] = As[tr * 4 + i][kk];
            #pragma unroll
            for (int j = 0; j < 4; ++j) b4[j] = Bs[tc * 4 + j][kk];
            #pragma unroll
            for (int i = 0; i < 4; ++i)
                #pragma unroll
                for (int j = 0; j < 4; ++j)
                    acc[i][j] += a4[i] * b4[j];
        }
        __syncthreads();
    }
    #pragma unroll
    for (int i = 0; i < 4; ++i) {
        int t = t0 + tr * 4 + i;
        int l = l_from_rn(t >> 10, t & 1023);
        #pragma unroll
        for (int j = 0; j < 4; ++j) {
            int c = c0 + tc * 4 + j;
            out[(size_t)l * 512 + c] = acc[i][j] + bias[c];
        }
    }
}

extern "C" void kernel_launch(void* const* d_in, const int* in_sizes, int n_in,
                              void* d_out, int out_size, void* d_ws, size_t ws_size,
                              hipStream_t stream) {
    const float* x      = (const float*)d_in[0];
    const float* qkv_w  = (const float*)d_in[1];
    const float* qkv_b  = (const float*)d_in[2];
    const float* proj_w = (const float*)d_in[3];
    const float* proj_b = (const float*)d_in[4];
    const float* epeg_w = (const float*)d_in[5];
    const float* epeg_b = (const float*)d_in[6];
    float* out = (float*)d_out;

    const size_t NQKV = (size_t)16 * 8 * 1024 * 64;   // 8388608 elems
    unsigned short* qb  = (unsigned short*)d_ws;
    unsigned short* kb  = qb + NQKV;
    unsigned short* vtb = kb + NQKV;
    float* ao = (float*)(vtb + NQKV);                 // [16384][512] fp32

    {
        dim3 grid(24, 256);
        qkv_kernel<<<grid, 256, 0, stream>>>(x, qkv_w, qkv_b, qb, kb, vtb);
    }
    {
        dim3 grid(16, 8, 16);
        attn_kernel<<<grid, 256, 0, stream>>>(qb, kb, vtb, epeg_w, epeg_b, ao);
    }
    {
        dim3 grid(8, 256);
        proj_kernel<<<grid, 256, 0, stream>>>(ao, proj_w, proj_b, out);
    }
}

// Round 3
// 230.991 us; speedup vs baseline: 7.1089x; 5.7806x over previous
//
#include <hip/hip_runtime.h>

// RegionAttention: bf16 MFMA everywhere (GEMMs + attention), fp32 accum.
// L=16384 -> 16 regions x 1024 tokens. HEADS=8, HD=64.
// ws: xb bf16[16M] | wqkv bf16[1.5M] | wproj bf16[0.5M] | q,k,vT bf16[16.8M each] | ao bf16[16.8M]

#define SCALE 0.125f

using bf16x8 = __attribute__((ext_vector_type(8))) short;
using f32x4  = __attribute__((ext_vector_type(4))) float;

__device__ __forceinline__ unsigned short f2bf(float f) {
    unsigned u = __float_as_uint(f);
    u += 0x7fff + ((u >> 16) & 1);
    return (unsigned short)(u >> 16);
}
__device__ __forceinline__ float bf2f(unsigned short s) {
    return __uint_as_float(((unsigned)s) << 16);
}
__device__ __forceinline__ void gload16(const void* g, void* l) {
    __builtin_amdgcn_global_load_lds(
        (const __attribute__((address_space(1))) void*)g,
        (__attribute__((address_space(3))) void*)l, 16, 0, 0);
}
__device__ __forceinline__ int l_from_rn(int region, int n) {
    int gi = region >> 2, gj = region & 3;
    int a = n >> 5, b = n & 31;
    return ((gi * 32 + a) << 7) + (gj << 5) + b;
}

// ---------------- cast kernels ----------------
__global__ __launch_bounds__(256) void cast_x_kernel(
    const float* __restrict__ x, unsigned short* __restrict__ xb)
{
    int tid = threadIdx.x;
    int t = blockIdx.x * 4 + (tid >> 6);
    int c8 = tid & 63;
    int l = l_from_rn(t >> 10, t & 1023);
    const float* src = x + (size_t)l * 512 + c8 * 8;
    float4 a = *(const float4*)src;
    float4 b = *(const float4*)(src + 4);
    bf16x8 o;
    o[0] = (short)f2bf(a.x); o[1] = (short)f2bf(a.y);
    o[2] = (short)f2bf(a.z); o[3] = (short)f2bf(a.w);
    o[4] = (short)f2bf(b.x); o[5] = (short)f2bf(b.y);
    o[6] = (short)f2bf(b.z); o[7] = (short)f2bf(b.w);
    *(bf16x8*)(xb + (size_t)t * 512 + c8 * 8) = o;
}

__global__ __launch_bounds__(256) void cast_w_kernel(
    const float* __restrict__ w, unsigned short* __restrict__ wb)
{
    int g = blockIdx.x * 256 + threadIdx.x;
    const float* src = w + (size_t)g * 8;
    float4 a = *(const float4*)src;
    float4 b = *(const float4*)(src + 4);
    bf16x8 o;
    o[0] = (short)f2bf(a.x); o[1] = (short)f2bf(a.y);
    o[2] = (short)f2bf(a.z); o[3] = (short)f2bf(a.w);
    o[4] = (short)f2bf(b.x); o[5] = (short)f2bf(b.y);
    o[6] = (short)f2bf(b.z); o[7] = (short)f2bf(b.w);
    *(bf16x8*)(wb + (size_t)g * 8) = o;
}

// ---------------- Kernel 1: QKV GEMM (bf16 MFMA) ----------------
// C[t][c] = sum_k xb[t][k]*wb[c][k] + bias[c]; scatter to q/k (row) and vT (col).
__global__ __launch_bounds__(256) void qkv_kernel(
    const unsigned short* __restrict__ xb, const unsigned short* __restrict__ wb,
    const float* __restrict__ bias, unsigned short* __restrict__ qo,
    unsigned short* __restrict__ ko, unsigned short* __restrict__ vto)
{
    __shared__ __align__(16) unsigned short As[128 * 64];
    __shared__ __align__(16) unsigned short Bs[128 * 64];
    const int c0t = blockIdx.x * 128;
    const int t0 = blockIdx.y * 128;
    const int tid = threadIdx.x;
    const int lane = tid & 63, w = tid >> 6;
    const int arow = lane & 15, kgrp = lane >> 4;
    const int wr = w >> 1, wc = w & 1;

    f32x4 acc[4][4];
    #pragma unroll
    for (int m = 0; m < 4; ++m)
        #pragma unroll
        for (int n = 0; n < 4; ++n) {
            f32x4 z = {0.f, 0.f, 0.f, 0.f};
            acc[m][n] = z;
        }

    for (int k0 = 0; k0 < 512; k0 += 64) {
        __syncthreads();
        #pragma unroll
        for (int it = 0; it < 4; ++it) {
            int slot = it * 256 + tid;
            int row = slot >> 3, phys = slot & 7;
            int c8 = phys ^ (row & 7);
            gload16(xb + (size_t)(t0 + row) * 512 + k0 + c8 * 8,
                    &As[(it * 256 + (w << 6)) * 8]);
            gload16(wb + (size_t)(c0t + row) * 512 + k0 + c8 * 8,
                    &Bs[(it * 256 + (w << 6)) * 8]);
        }
        __syncthreads();

        bf16x8 af[4][2], bfr[4][2];
        #pragma unroll
        for (int m = 0; m < 4; ++m) {
            int r = wr * 64 + m * 16 + arow;
            af[m][0] = *(const bf16x8*)&As[r * 64 + ((kgrp ^ (r & 7)) * 8)];
            af[m][1] = *(const bf16x8*)&As[r * 64 + (((4 + kgrp) ^ (r & 7)) * 8)];
        }
        #pragma unroll
        for (int n = 0; n < 4; ++n) {
            int r = wc * 64 + n * 16 + arow;
            bfr[n][0] = *(const bf16x8*)&Bs[r * 64 + ((kgrp ^ (r & 7)) * 8)];
            bfr[n][1] = *(const bf16x8*)&Bs[r * 64 + (((4 + kgrp) ^ (r & 7)) * 8)];
        }
        #pragma unroll
        for (int m = 0; m < 4; ++m)
            #pragma unroll
            for (int n = 0; n < 4; ++n) {
                acc[m][n] = __builtin_amdgcn_mfma_f32_16x16x32_bf16(
                    af[m][0], bfr[n][0], acc[m][n], 0, 0, 0);
                acc[m][n] = __builtin_amdgcn_mfma_f32_16x16x32_bf16(
                    af[m][1], bfr[n][1], acc[m][n], 0, 0, 0);
            }
    }

    const int s = c0t >> 9;
    const int region = t0 >> 10;
    #pragma unroll
    for (int n = 0; n < 4; ++n) {
        int cg = c0t + wc * 64 + n * 16 + arow;
        float bi = bias[cg];
        int h = (cg >> 6) & 7, d = cg & 63;
        if (s < 2) {
            unsigned short* dst = (s == 0) ? qo : ko;
            #pragma unroll
            for (int m = 0; m < 4; ++m) {
                int tb = t0 + wr * 64 + m * 16 + kgrp * 4;
                unsigned short* p =
                    dst + ((size_t)(region * 8 + h) * 1024 + (tb & 1023)) * 64 + d;
                #pragma unroll
                for (int i = 0; i < 4; ++i)
                    p[(size_t)i * 64] = f2bf(acc[m][n][i] + bi);
            }
        } else {
            #pragma unroll
            for (int m = 0; m < 4; ++m) {
                int tb = t0 + wr * 64 + m * 16 + kgrp * 4;
                ushort4 pk;
                pk.x = f2bf(acc[m][n][0] + bi);
                pk.y = f2bf(acc[m][n][1] + bi);
                pk.z = f2bf(acc[m][n][2] + bi);
                pk.w = f2bf(acc[m][n][3] + bi);
                *(ushort4*)(vto + (size_t)(region * 8 + h) * 65536 +
                            (size_t)d * 1024 + (tb & 1023)) = pk;
            }
        }
    }
}

// ---------------- Kernel 2: bf16 MFMA attention + fused EPEG conv/softmax ----------
__global__ __launch_bounds__(256) void attn_kernel(
    const unsigned short* __restrict__ qg, const unsigned short* __restrict__ kg,
    const unsigned short* __restrict__ vtg, const float* __restrict__ epw,
    const float* __restrict__ epb, unsigned short* __restrict__ ao)
{
    const int rb = blockIdx.x, head = blockIdx.y, region = blockIdx.z;
    const int rh = region * 8 + head;
    const unsigned short* qb = qg + (size_t)rh * 65536;
    const unsigned short* kb = kg + (size_t)rh * 65536;
    const unsigned short* vb = vtg + (size_t)rh * 65536;
    const int i0 = rb * 64;
    const int tid = threadIdx.x;
    const int lane = tid & 63, w = tid >> 6;
    const int arow = lane & 15, kgrp = lane >> 4;

    __shared__ __align__(16) unsigned short Ks[64 * 64];
    __shared__ __align__(16) unsigned short VTs[64 * 64];
    __shared__ __align__(16) unsigned short Ps[64 * 64];
    __shared__ __align__(16) float Ss[68][68];
    __shared__ __align__(16) unsigned short Qh[4 * 64];
    __shared__ float row_scale[64];
    __shared__ float row_l[64];

    bf16x8 qf0, qf1;
    {
        const unsigned short* p = qb + (size_t)(i0 + w * 16 + arow) * 64 + kgrp * 8;
        qf0 = *(const bf16x8*)p;
        qf1 = *(const bf16x8*)(p + 32);
    }
    if (tid < 32) {
        int hr = tid >> 3, c8 = tid & 7;
        int gi = (hr < 2) ? (i0 - 2 + hr) : (i0 + 62 + hr);
        bf16x8 val;
        #pragma unroll
        for (int e = 0; e < 8; ++e) val[e] = 0;
        if (gi >= 0 && gi < 1024)
            val = *(const bf16x8*)(qb + (size_t)gi * 64 + c8 * 8);
        *(bf16x8*)&Qh[hr * 64 + c8 * 8] = val;
    }

    float cw[5];
    #pragma unroll
    for (int t = 0; t < 5; ++t) cw[t] = epw[head * 5 + t];
    const float cb = epb[head];

    const int srow = tid >> 2, scol = tid & 3;
    float m_r = -1e30f, l_r = 0.f;
    f32x4 oacc[4];
    #pragma unroll
    for (int dt = 0; dt < 4; ++dt) {
        f32x4 z = {0.f, 0.f, 0.f, 0.f};
        oacc[dt] = z;
    }

    for (int jt = 0; jt < 16; ++jt) {
        const int j0 = jt * 64;
        __syncthreads();
        #pragma unroll
        for (int it = 0; it < 2; ++it) {
            int q = (it * 4 + w) * 64 + lane;
            int row = q >> 3, phys = q & 7, c8 = phys ^ (row & 7);
            gload16(kb + (size_t)(j0 + row) * 64 + c8 * 8, &Ks[(it * 4 + w) * 512]);
            gload16(vb + (size_t)row * 1024 + j0 + c8 * 8, &VTs[(it * 4 + w) * 512]);
        }
        __syncthreads();

        #pragma unroll
        for (int ct = 0; ct < 4; ++ct) {
            f32x4 sacc = {0.f, 0.f, 0.f, 0.f};
            int krow = ct * 16 + arow;
            int ph0 = kgrp ^ (krow & 7);
            int ph1 = (4 + kgrp) ^ (krow & 7);
            bf16x8 kf0 = *(const bf16x8*)&Ks[krow * 64 + ph0 * 8];
            bf16x8 kf1 = *(const bf16x8*)&Ks[krow * 64 + ph1 * 8];
            sacc = __builtin_amdgcn_mfma_f32_16x16x32_bf16(qf0, kf0, sacc, 0, 0, 0);
            sacc = __builtin_amdgcn_mfma_f32_16x16x32_bf16(qf1, kf1, sacc, 0, 0, 0);
            int sc_ = ct * 16 + arow;
            int sr = 2 + w * 16 + kgrp * 4;
            #pragma unroll
            for (int i = 0; i < 4; ++i) Ss[sr + i][sc_] = sacc[i] * SCALE;
        }
        {
            int hr = w, hc = lane;
            float dot = 0.f;
            #pragma unroll
            for (int c8 = 0; c8 < 8; ++c8) {
                bf16x8 qv = *(const bf16x8*)&Qh[hr * 64 + c8 * 8];
                int ph = c8 ^ (hc & 7);
                bf16x8 kv = *(const bf16x8*)&Ks[hc * 64 + ph * 8];
                #pragma unroll
                for (int e = 0; e < 8; ++e)
                    dot += bf2f((unsigned short)qv[e]) * bf2f((unsigned short)kv[e]);
            }
            int hsr = (hr < 2) ? hr : hr + 64;
            Ss[hsr][hc] = dot * SCALE;
        }
        __syncthreads();

        float st[16];
        float mx = -1e30f;
        {
            int r = srow, cb0 = scol * 16;
            #pragma unroll
            for (int cc = 0; cc < 4; ++cc) {
                float4 a0 = *(const float4*)&Ss[r + 0][cb0 + cc * 4];
                float4 a1 = *(const float4*)&Ss[r + 1][cb0 + cc * 4];
                float4 a2 = *(const float4*)&Ss[r + 2][cb0 + cc * 4];
                float4 a3 = *(const float4*)&Ss[r + 3][cb0 + cc * 4];
                float4 a4 = *(const float4*)&Ss[r + 4][cb0 + cc * 4];
                float v0 = a2.x + cb + cw[0]*a0.x + cw[1]*a1.x + cw[2]*a2.x + cw[3]*a3.x + cw[4]*a4.x;
                float v1 = a2.y + cb + cw[0]*a0.y + cw[1]*a1.y + cw[2]*a2.y + cw[3]*a3.y + cw[4]*a4.y;
                float v2 = a2.z + cb + cw[0]*a0.z + cw[1]*a1.z + cw[2]*a2.z + cw[3]*a3.z + cw[4]*a4.z;
                float v3 = a2.w + cb + cw[0]*a0.w + cw[1]*a1.w + cw[2]*a2.w + cw[3]*a3.w + cw[4]*a4.w;
                st[cc * 4 + 0] = v0; st[cc * 4 + 1] = v1;
                st[cc * 4 + 2] = v2; st[cc * 4 + 3] = v3;
                mx = fmaxf(mx, fmaxf(fmaxf(v0, v1), fmaxf(v2, v3)));
            }
        }
        mx = fmaxf(mx, __shfl_xor(mx, 1));
        mx = fmaxf(mx, __shfl_xor(mx, 2));
        float mnew = fmaxf(m_r, mx);
        float scl = __expf(m_r - mnew);
        float ssum = 0.f;
        #pragma unroll
        for (int j = 0; j < 16; ++j) {
            st[j] = __expf(st[j] - mnew);
            ssum += st[j];
        }
        ssum += __shfl_xor(ssum, 1);
        ssum += __shfl_xor(ssum, 2);
        m_r = mnew;
        l_r = l_r * scl + ssum;
        if (scol == 0) row_scale[srow] = scl;

        {
            int r = srow;
            #pragma unroll
            for (int e = 0; e < 2; ++e) {
                bf16x8 pk;
                #pragma unroll
                for (int e2 = 0; e2 < 8; ++e2)
                    pk[e2] = (short)f2bf(st[e * 8 + e2]);
                int ch = scol * 2 + e;
                *(bf16x8*)&Ps[r * 64 + ((ch ^ (r & 7)) * 8)] = pk;
            }
        }
        {
            int prow = w * 16 + arow;
            int pp0 = kgrp ^ (prow & 7);
            int pp1 = (4 + kgrp) ^ (prow & 7);
            bf16x8 pf0 = *(const bf16x8*)&Ps[prow * 64 + pp0 * 8];
            bf16x8 pf1 = *(const bf16x8*)&Ps[prow * 64 + pp1 * 8];
            float rs[4];
            #pragma unroll
            for (int i = 0; i < 4; ++i) rs[i] = row_scale[w * 16 + kgrp * 4 + i];
            #pragma unroll
            for (int dt = 0; dt < 4; ++dt) {
                int drow = dt * 16 + arow;
                int vp0 = kgrp ^ (drow & 7);
                int vp1 = (4 + kgrp) ^ (drow & 7);
                bf16x8 vf0 = *(const bf16x8*)&VTs[drow * 64 + vp0 * 8];
                bf16x8 vf1 = *(const bf16x8*)&VTs[drow * 64 + vp1 * 8];
                f32x4 t = oacc[dt];
                #pragma unroll
                for (int i = 0; i < 4; ++i) t[i] *= rs[i];
                t = __builtin_amdgcn_mfma_f32_16x16x32_bf16(pf0, vf0, t, 0, 0, 0);
                t = __builtin_amdgcn_mfma_f32_16x16x32_bf16(pf1, vf1, t, 0, 0, 0);
                oacc[dt] = t;
            }
        }
    }

    if (scol == 0) row_l[srow] = l_r;
    __syncthreads();
    float inv[4];
    #pragma unroll
    for (int i = 0; i < 4; ++i) inv[i] = 1.f / row_l[w * 16 + kgrp * 4 + i];
    #pragma unroll
    for (int dt = 0; dt < 4; ++dt) {
        #pragma unroll
        for (int i = 0; i < 4; ++i) {
            size_t t = (size_t)region * 1024 + i0 + w * 16 + kgrp * 4 + i;
            ao[t * 512 + head * 64 + dt * 16 + arow] = f2bf(oacc[dt][i] * inv[i]);
        }
    }
}

// ---------------- Kernel 3: proj GEMM (bf16 MFMA, fp32 out, un-permute) -------------
__global__ __launch_bounds__(256) void proj_kernel(
    const unsigned short* __restrict__ ab, const unsigned short* __restrict__ wb,
    const float* __restrict__ bias, float* __restrict__ out)
{
    __shared__ __align__(16) unsigned short As[128 * 64];
    __shared__ __align__(16) unsigned short Bs[128 * 64];
    const int c0t = blockIdx.x * 128;
    const int t0 = blockIdx.y * 128;
    const int tid = threadIdx.x;
    const int lane = tid & 63, w = tid >> 6;
    const int arow = lane & 15, kgrp = lane >> 4;
    const int wr = w >> 1, wc = w & 1;

    f32x4 acc[4][4];
    #pragma unroll
    for (int m = 0; m < 4; ++m)
        #pragma unroll
        for (int n = 0; n < 4; ++n) {
            f32x4 z = {0.f, 0.f, 0.f, 0.f};
            acc[m][n] = z;
        }

    for (int k0 = 0; k0 < 512; k0 += 64) {
        __syncthreads();
        #pragma unroll
        for (int it = 0; it < 4; ++it) {
            int slot = it * 256 + tid;
            int row = slot >> 3, phys = slot & 7;
            int c8 = phys ^ (row & 7);
            gload16(ab + (size_t)(t0 + row) * 512 + k0 + c8 * 8,
                    &As[(it * 256 + (w << 6)) * 8]);
            gload16(wb + (size_t)(c0t + row) * 512 + k0 + c8 * 8,
                    &Bs[(it * 256 + (w << 6)) * 8]);
        }
        __syncthreads();

        bf16x8 af[4][2], bfr[4][2];
        #pragma unroll
        for (int m = 0; m < 4; ++m) {
            int r = wr * 64 + m * 16 + arow;
            af[m][0] = *(const bf16x8*)&As[r * 64 + ((kgrp ^ (r & 7)) * 8)];
            af[m][1] = *(const bf16x8*)&As[r * 64 + (((4 + kgrp) ^ (r & 7)) * 8)];
        }
        #pragma unroll
        for (int n = 0; n < 4; ++n) {
            int r = wc * 64 + n * 16 + arow;
            bfr[n][0] = *(const bf16x8*)&Bs[r * 64 + ((kgrp ^ (r & 7)) * 8)];
            bfr[n][1] = *(const bf16x8*)&Bs[r * 64 + (((4 + kgrp) ^ (r & 7)) * 8)];
        }
        #pragma unroll
        for (int m = 0; m < 4; ++m)
            #pragma unroll
            for (int n = 0; n < 4; ++n) {
                acc[m][n] = __builtin_amdgcn_mfma_f32_16x16x32_bf16(
                    af[m][0], bfr[n][0], acc[m][n], 0, 0, 0);
                acc[m][n] = __builtin_amdgcn_mfma_f32_16x16x32_bf16(
                    af[m][1], bfr[n][1], acc[m][n], 0, 0, 0);
            }
    }

    #pragma unroll
    for (int n = 0; n < 4; ++n) {
        int cg = c0t + wc * 64 + n * 16 + arow;
        float bi = bias[cg];
        #pragma unroll
        for (int m = 0; m < 4; ++m) {
            int tb = t0 + wr * 64 + m * 16 + kgrp * 4;
            int l0 = l_from_rn(tb >> 10, tb & 1023);
            float* p = out + (size_t)l0 * 512 + cg;
            #pragma unroll
            for (int i = 0; i < 4; ++i)
                p[(size_t)i * 512] = acc[m][n][i] + bi;
        }
    }
}

extern "C" void kernel_launch(void* const* d_in, const int* in_sizes, int n_in,
                              void* d_out, int out_size, void* d_ws, size_t ws_size,
                              hipStream_t stream) {
    const float* x      = (const float*)d_in[0];
    const float* qkv_w  = (const float*)d_in[1];
    const float* qkv_b  = (const float*)d_in[2];
    const float* proj_w = (const float*)d_in[3];
    const float* proj_b = (const float*)d_in[4];
    const float* epeg_w = (const float*)d_in[5];
    const float* epeg_b = (const float*)d_in[6];
    float* out = (float*)d_out;

    const size_t NTOK = (size_t)16384 * 512;          // 8388608
    unsigned short* xb    = (unsigned short*)d_ws;    // [16384][512]
    unsigned short* wqkv  = xb + NTOK;                // [1536][512]
    unsigned short* wproj = wqkv + (size_t)1536 * 512;
    unsigned short* qb    = wproj + (size_t)512 * 512;
    unsigned short* kb    = qb + NTOK;
    unsigned short* vtb   = kb + NTOK;
    unsigned short* ao    = vtb + NTOK;               // [16384][512] bf16

    cast_x_kernel<<<4096, 256, 0, stream>>>(x, xb);
    cast_w_kernel<<<384, 256, 0, stream>>>(qkv_w, wqkv);
    cast_w_kernel<<<128, 256, 0, stream>>>(proj_w, wproj);
    {
        dim3 grid(12, 128);
        qkv_kernel<<<grid, 256, 0, stream>>>(xb, wqkv, qkv_b, qb, kb, vtb);
    }
    {
        dim3 grid(16, 8, 16);
        attn_kernel<<<grid, 256, 0, stream>>>(qb, kb, vtb, epeg_w, epeg_b, ao);
    }
    {
        dim3 grid(4, 128);
        proj_kernel<<<grid, 256, 0, stream>>>(ao, wproj, proj_b, out);
    }
}

// Round 4
// 195.686 us; speedup vs baseline: 8.3914x; 1.1804x over previous
//
#include <hip/hip_runtime.h>

// RegionAttention: bf16 MFMA everywhere (GEMMs + attention), fp32 accum.
// L=16384 -> 16 regions x 1024 tokens. HEADS=8, HD=64.
// ws: xb bf16[16M] | wqkv bf16[1.5M] | wproj bf16[0.5M] | q,k,vT bf16 | ao bf16
// q is stored PRE-SCALED by 0.125 (folded attention scale).

using bf16x8 = __attribute__((ext_vector_type(8))) short;
using f32x4  = __attribute__((ext_vector_type(4))) float;

__device__ __forceinline__ unsigned short f2bf(float f) {
    unsigned u = __float_as_uint(f);
    u += 0x7fff + ((u >> 16) & 1);
    return (unsigned short)(u >> 16);
}
__device__ __forceinline__ unsigned short f2bf_fast(float f) {
    unsigned u = __float_as_uint(f);
    return (unsigned short)((u + 0x8000u) >> 16);
}
__device__ __forceinline__ void gload16(const void* g, void* l) {
    __builtin_amdgcn_global_load_lds(
        (const __attribute__((address_space(1))) void*)g,
        (__attribute__((address_space(3))) void*)l, 16, 0, 0);
}
__device__ __forceinline__ int l_from_rn(int region, int n) {
    int gi = region >> 2, gj = region & 3;
    int a = n >> 5, b = n & 31;
    return ((gi * 32 + a) << 7) + (gj << 5) + b;
}

// ---------------- cast kernels ----------------
__global__ __launch_bounds__(256) void cast_x_kernel(
    const float* __restrict__ x, unsigned short* __restrict__ xb)
{
    int tid = threadIdx.x;
    int t = blockIdx.x * 4 + (tid >> 6);
    int c8 = tid & 63;
    int l = l_from_rn(t >> 10, t & 1023);
    const float* src = x + (size_t)l * 512 + c8 * 8;
    float4 a = *(const float4*)src;
    float4 b = *(const float4*)(src + 4);
    bf16x8 o;
    o[0] = (short)f2bf(a.x); o[1] = (short)f2bf(a.y);
    o[2] = (short)f2bf(a.z); o[3] = (short)f2bf(a.w);
    o[4] = (short)f2bf(b.x); o[5] = (short)f2bf(b.y);
    o[6] = (short)f2bf(b.z); o[7] = (short)f2bf(b.w);
    *(bf16x8*)(xb + (size_t)t * 512 + c8 * 8) = o;
}

__global__ __launch_bounds__(256) void cast_w_kernel(
    const float* __restrict__ w, unsigned short* __restrict__ wb)
{
    int g = blockIdx.x * 256 + threadIdx.x;
    const float* src = w + (size_t)g * 8;
    float4 a = *(const float4*)src;
    float4 b = *(const float4*)(src + 4);
    bf16x8 o;
    o[0] = (short)f2bf(a.x); o[1] = (short)f2bf(a.y);
    o[2] = (short)f2bf(a.z); o[3] = (short)f2bf(a.w);
    o[4] = (short)f2bf(b.x); o[5] = (short)f2bf(b.y);
    o[6] = (short)f2bf(b.z); o[7] = (short)f2bf(b.w);
    *(bf16x8*)(wb + (size_t)g * 8) = o;
}

// ---------------- Kernel 1: QKV GEMM (bf16 MFMA) ----------------
__global__ __launch_bounds__(256) void qkv_kernel(
    const unsigned short* __restrict__ xb, const unsigned short* __restrict__ wb,
    const float* __restrict__ bias, unsigned short* __restrict__ qo,
    unsigned short* __restrict__ ko, unsigned short* __restrict__ vto)
{
    __shared__ __align__(16) unsigned short As[128 * 64];
    __shared__ __align__(16) unsigned short Bs[128 * 64];
    const int c0t = blockIdx.x * 128;
    const int t0 = blockIdx.y * 128;
    const int tid = threadIdx.x;
    const int lane = tid & 63, w = tid >> 6;
    const int arow = lane & 15, kgrp = lane >> 4;
    const int wr = w >> 1, wc = w & 1;

    f32x4 acc[4][4];
    #pragma unroll
    for (int m = 0; m < 4; ++m)
        #pragma unroll
        for (int n = 0; n < 4; ++n) {
            f32x4 z = {0.f, 0.f, 0.f, 0.f};
            acc[m][n] = z;
        }

    for (int k0 = 0; k0 < 512; k0 += 64) {
        __syncthreads();
        #pragma unroll
        for (int it = 0; it < 4; ++it) {
            int slot = it * 256 + tid;
            int row = slot >> 3, phys = slot & 7;
            int c8 = phys ^ (row & 7);
            gload16(xb + (size_t)(t0 + row) * 512 + k0 + c8 * 8,
                    &As[(it * 256 + (w << 6)) * 8]);
            gload16(wb + (size_t)(c0t + row) * 512 + k0 + c8 * 8,
                    &Bs[(it * 256 + (w << 6)) * 8]);
        }
        __syncthreads();

        bf16x8 af[4][2], bfr[4][2];
        #pragma unroll
        for (int m = 0; m < 4; ++m) {
            int r = wr * 64 + m * 16 + arow;
            af[m][0] = *(const bf16x8*)&As[r * 64 + ((kgrp ^ (r & 7)) * 8)];
            af[m][1] = *(const bf16x8*)&As[r * 64 + (((4 + kgrp) ^ (r & 7)) * 8)];
        }
        #pragma unroll
        for (int n = 0; n < 4; ++n) {
            int r = wc * 64 + n * 16 + arow;
            bfr[n][0] = *(const bf16x8*)&Bs[r * 64 + ((kgrp ^ (r & 7)) * 8)];
            bfr[n][1] = *(const bf16x8*)&Bs[r * 64 + (((4 + kgrp) ^ (r & 7)) * 8)];
        }
        #pragma unroll
        for (int m = 0; m < 4; ++m)
            #pragma unroll
            for (int n = 0; n < 4; ++n) {
                acc[m][n] = __builtin_amdgcn_mfma_f32_16x16x32_bf16(
                    af[m][0], bfr[n][0], acc[m][n], 0, 0, 0);
                acc[m][n] = __builtin_amdgcn_mfma_f32_16x16x32_bf16(
                    af[m][1], bfr[n][1], acc[m][n], 0, 0, 0);
            }
    }

    const int s = c0t >> 9;
    const int region = t0 >> 10;
    const float qs = (s == 0) ? 0.125f : 1.0f;   // fold attention scale into q
    #pragma unroll
    for (int n = 0; n < 4; ++n) {
        int cg = c0t + wc * 64 + n * 16 + arow;
        float bi = bias[cg];
        int h = (cg >> 6) & 7, d = cg & 63;
        if (s < 2) {
            unsigned short* dst = (s == 0) ? qo : ko;
            #pragma unroll
            for (int m = 0; m < 4; ++m) {
                int tb = t0 + wr * 64 + m * 16 + kgrp * 4;
                unsigned short* p =
                    dst + ((size_t)(region * 8 + h) * 1024 + (tb & 1023)) * 64 + d;
                #pragma unroll
                for (int i = 0; i < 4; ++i)
                    p[(size_t)i * 64] = f2bf((acc[m][n][i] + bi) * qs);
            }
        } else {
            #pragma unroll
            for (int m = 0; m < 4; ++m) {
                int tb = t0 + wr * 64 + m * 16 + kgrp * 4;
                ushort4 pk;
                pk.x = f2bf(acc[m][n][0] + bi);
                pk.y = f2bf(acc[m][n][1] + bi);
                pk.z = f2bf(acc[m][n][2] + bi);
                pk.w = f2bf(acc[m][n][3] + bi);
                *(ushort4*)(vto + (size_t)(region * 8 + h) * 65536 +
                            (size_t)d * 1024 + (tb & 1023)) = pk;
            }
        }
    }
}

// ---------------- Kernel 2: bf16 MFMA attention + fused EPEG conv/softmax ----------
// Double-buffered K/VT staging; P aliases the retired K buffer; halo via MFMA.
__global__ __launch_bounds__(256) void attn_kernel(
    const unsigned short* __restrict__ qg, const unsigned short* __restrict__ kg,
    const unsigned short* __restrict__ vtg, const float* __restrict__ epw,
    const float* __restrict__ epb, unsigned short* __restrict__ ao)
{
    const int rb = blockIdx.x, head = blockIdx.y, region = blockIdx.z;
    const int rh = region * 8 + head;
    const unsigned short* qb = qg + (size_t)rh * 65536;
    const unsigned short* kb = kg + (size_t)rh * 65536;
    const unsigned short* vb = vtg + (size_t)rh * 65536;
    const int i0 = rb * 64;
    const int tid = threadIdx.x;
    const int lane = tid & 63, w = tid >> 6;
    const int arow = lane & 15, kgrp = lane >> 4;

    __shared__ __align__(16) unsigned short Ks[2][64 * 64];
    __shared__ __align__(16) unsigned short VTs[2][64 * 64];
    __shared__ __align__(16) float Ss[68][68];
    __shared__ float row_scale[64];
    __shared__ float row_l[64];

    // Q fragments (pre-scaled by 0.125 in qkv)
    bf16x8 qf0, qf1;
    {
        const unsigned short* p = qb + (size_t)(i0 + w * 16 + arow) * 64 + kgrp * 8;
        qf0 = *(const bf16x8*)p;
        qf1 = *(const bf16x8*)(p + 32);
    }
    // halo Q fragment: A-rows 0..3 = q rows {i0-2,i0-1,i0+64,i0+65}, rest zero
    bf16x8 qhf0, qhf1;
    #pragma unroll
    for (int e = 0; e < 8; ++e) { qhf0[e] = 0; qhf1[e] = 0; }
    {
        int gi = (arow < 2) ? (i0 - 2 + arow) : (i0 + 62 + arow);
        if (arow < 4 && gi >= 0 && gi < 1024) {
            const unsigned short* p = qb + (size_t)gi * 64 + kgrp * 8;
            qhf0 = *(const bf16x8*)p;
            qhf1 = *(const bf16x8*)(p + 32);
        }
    }

    // conv taps folded with log2e and the direct-S term
    const float LOG2E = 1.4426950408889634f;
    float cwt[5];
    #pragma unroll
    for (int t = 0; t < 5; ++t) cwt[t] = epw[head * 5 + t] * LOG2E;
    cwt[2] += LOG2E;
    const float cbt = epb[head] * LOG2E;

    const int srow = tid >> 2, scol = tid & 3;
    float m_r = -1e30f, l_r = 0.f;
    f32x4 oacc[4];
    #pragma unroll
    for (int dt = 0; dt < 4; ++dt) {
        f32x4 z = {0.f, 0.f, 0.f, 0.f};
        oacc[dt] = z;
    }

    auto stage = [&](int jt, int buf) {
        const int j0 = jt * 64;
        #pragma unroll
        for (int it = 0; it < 2; ++it) {
            int q_ = (it * 4 + w) * 64 + lane;
            int row = q_ >> 3, phys = q_ & 7, c8 = phys ^ (row & 7);
            gload16(kb + (size_t)(j0 + row) * 64 + c8 * 8,
                    &Ks[buf][(it * 4 + w) * 512]);
            gload16(vb + (size_t)row * 1024 + j0 + c8 * 8,
                    &VTs[buf][(it * 4 + w) * 512]);
        }
    };

    stage(0, 0);

    for (int jt = 0; jt < 16; ++jt) {
        const int cur = jt & 1;
        __syncthreads();   // drains staged vmcnt; Ss + buf[cur^1] safe to reuse
        if (jt < 15) stage(jt + 1, cur ^ 1);   // in flight until next top barrier

        const unsigned short* Kc = &Ks[cur][0];
        // S = Q K^T via MFMA; wave w owns rows [w*16, w*16+16); halo on ct==w
        #pragma unroll
        for (int ct = 0; ct < 4; ++ct) {
            f32x4 sacc = {0.f, 0.f, 0.f, 0.f};
            int krow = ct * 16 + arow;
            int ph0 = kgrp ^ (krow & 7);
            int ph1 = (4 + kgrp) ^ (krow & 7);
            bf16x8 kf0 = *(const bf16x8*)&Kc[krow * 64 + ph0 * 8];
            bf16x8 kf1 = *(const bf16x8*)&Kc[krow * 64 + ph1 * 8];
            sacc = __builtin_amdgcn_mfma_f32_16x16x32_bf16(qf0, kf0, sacc, 0, 0, 0);
            sacc = __builtin_amdgcn_mfma_f32_16x16x32_bf16(qf1, kf1, sacc, 0, 0, 0);
            int sc_ = ct * 16 + arow;
            int sr = 2 + w * 16 + kgrp * 4;
            #pragma unroll
            for (int i = 0; i < 4; ++i) Ss[sr + i][sc_] = sacc[i];
            if (ct == w) {   // halo rows for this wave's column quarter
                f32x4 hacc = {0.f, 0.f, 0.f, 0.f};
                hacc = __builtin_amdgcn_mfma_f32_16x16x32_bf16(qhf0, kf0, hacc, 0, 0, 0);
                hacc = __builtin_amdgcn_mfma_f32_16x16x32_bf16(qhf1, kf1, hacc, 0, 0, 0);
                if (kgrp == 0) {
                    Ss[0][sc_]  = hacc[0];
                    Ss[1][sc_]  = hacc[1];
                    Ss[66][sc_] = hacc[2];
                    Ss[67][sc_] = hacc[3];
                }
            }
        }
        // S visible to all waves; do NOT drain vmcnt (keep prefetch in flight)
        asm volatile("s_waitcnt lgkmcnt(0)\n\ts_barrier" ::: "memory");

        // conv + online softmax (exp2 domain): 4 threads/row, 16 cols each
        float st[16];
        float mx = -1e30f;
        {
            int r = srow, cb0 = scol * 16;
            #pragma unroll
            for (int cc = 0; cc < 4; ++cc) {
                float4 a0 = *(const float4*)&Ss[r + 0][cb0 + cc * 4];
                float4 a1 = *(const float4*)&Ss[r + 1][cb0 + cc * 4];
                float4 a2 = *(const float4*)&Ss[r + 2][cb0 + cc * 4];
                float4 a3 = *(const float4*)&Ss[r + 3][cb0 + cc * 4];
                float4 a4 = *(const float4*)&Ss[r + 4][cb0 + cc * 4];
                float v0 = cbt + cwt[0]*a0.x + cwt[1]*a1.x + cwt[2]*a2.x + cwt[3]*a3.x + cwt[4]*a4.x;
                float v1 = cbt + cwt[0]*a0.y + cwt[1]*a1.y + cwt[2]*a2.y + cwt[3]*a3.y + cwt[4]*a4.y;
                float v2 = cbt + cwt[0]*a0.z + cwt[1]*a1.z + cwt[2]*a2.z + cwt[3]*a3.z + cwt[4]*a4.z;
                float v3 = cbt + cwt[0]*a0.w + cwt[1]*a1.w + cwt[2]*a2.w + cwt[3]*a3.w + cwt[4]*a4.w;
                st[cc * 4 + 0] = v0; st[cc * 4 + 1] = v1;
                st[cc * 4 + 2] = v2; st[cc * 4 + 3] = v3;
                mx = fmaxf(mx, fmaxf(fmaxf(v0, v1), fmaxf(v2, v3)));
            }
        }
        mx = fmaxf(mx, __shfl_xor(mx, 1));
        mx = fmaxf(mx, __shfl_xor(mx, 2));
        float mnew = fmaxf(m_r, mx);
        float scl = exp2f(m_r - mnew);
        float ssum = 0.f;
        #pragma unroll
        for (int j = 0; j < 16; ++j) {
            st[j] = exp2f(st[j] - mnew);
            ssum += st[j];
        }
        ssum += __shfl_xor(ssum, 1);
        ssum += __shfl_xor(ssum, 2);
        m_r = mnew;
        l_r = l_r * scl + ssum;
        if (scol == 0) row_scale[srow] = scl;

        // P -> bf16, aliasing the retired K buffer (all S reads of it are done)
        unsigned short* Pp = &Ks[cur][0];
        {
            int r = srow;
            #pragma unroll
            for (int e = 0; e < 2; ++e) {
                bf16x8 pk;
                #pragma unroll
                for (int e2 = 0; e2 < 8; ++e2)
                    pk[e2] = (short)f2bf_fast(st[e * 8 + e2]);
                int ch = scol * 2 + e;
                *(bf16x8*)&Pp[r * 64 + ((ch ^ (r & 7)) * 8)] = pk;
            }
        }
        // PV MFMA (wave-local LDS reads)
        {
            const unsigned short* Vc = &VTs[cur][0];
            int prow = w * 16 + arow;
            int pp0 = kgrp ^ (prow & 7);
            int pp1 = (4 + kgrp) ^ (prow & 7);
            bf16x8 pf0 = *(const bf16x8*)&Pp[prow * 64 + pp0 * 8];
            bf16x8 pf1 = *(const bf16x8*)&Pp[prow * 64 + pp1 * 8];
            float rs[4];
            #pragma unroll
            for (int i = 0; i < 4; ++i) rs[i] = row_scale[w * 16 + kgrp * 4 + i];
            #pragma unroll
            for (int dt = 0; dt < 4; ++dt) {
                int drow = dt * 16 + arow;
                int vp0 = kgrp ^ (drow & 7);
                int vp1 = (4 + kgrp) ^ (drow & 7);
                bf16x8 vf0 = *(const bf16x8*)&Vc[drow * 64 + vp0 * 8];
                bf16x8 vf1 = *(const bf16x8*)&Vc[drow * 64 + vp1 * 8];
                f32x4 t = oacc[dt];
                #pragma unroll
                for (int i = 0; i < 4; ++i) t[i] *= rs[i];
                t = __builtin_amdgcn_mfma_f32_16x16x32_bf16(pf0, vf0, t, 0, 0, 0);
                t = __builtin_amdgcn_mfma_f32_16x16x32_bf16(pf1, vf1, t, 0, 0, 0);
                oacc[dt] = t;
            }
        }
    }

    if (scol == 0) row_l[srow] = l_r;
    __syncthreads();
    float inv[4];
    #pragma unroll
    for (int i = 0; i < 4; ++i) inv[i] = 1.f / row_l[w * 16 + kgrp * 4 + i];
    #pragma unroll
    for (int dt = 0; dt < 4; ++dt) {
        #pragma unroll
        for (int i = 0; i < 4; ++i) {
            size_t t = (size_t)region * 1024 + i0 + w * 16 + kgrp * 4 + i;
            ao[t * 512 + head * 64 + dt * 16 + arow] = f2bf(oacc[dt][i] * inv[i]);
        }
    }
}

// ---------------- Kernel 3: proj GEMM (bf16 MFMA, fp32 out, un-permute) -------------
__global__ __launch_bounds__(256) void proj_kernel(
    const unsigned short* __restrict__ ab, const unsigned short* __restrict__ wb,
    const float* __restrict__ bias, float* __restrict__ out)
{
    __shared__ __align__(16) unsigned short As[128 * 64];
    __shared__ __align__(16) unsigned short Bs[128 * 64];
    const int c0t = blockIdx.x * 128;
    const int t0 = blockIdx.y * 128;
    const int tid = threadIdx.x;
    const int lane = tid & 63, w = tid >> 6;
    const int arow = lane & 15, kgrp = lane >> 4;
    const int wr = w >> 1, wc = w & 1;

    f32x4 acc[4][4];
    #pragma unroll
    for (int m = 0; m < 4; ++m)
        #pragma unroll
        for (int n = 0; n < 4; ++n) {
            f32x4 z = {0.f, 0.f, 0.f, 0.f};
            acc[m][n] = z;
        }

    for (int k0 = 0; k0 < 512; k0 += 64) {
        __syncthreads();
        #pragma unroll
        for (int it = 0; it < 4; ++it) {
            int slot = it * 256 + tid;
            int row = slot >> 3, phys = slot & 7;
            int c8 = phys ^ (row & 7);
            gload16(ab + (size_t)(t0 + row) * 512 + k0 + c8 * 8,
                    &As[(it * 256 + (w << 6)) * 8]);
            gload16(wb + (size_t)(c0t + row) * 512 + k0 + c8 * 8,
                    &Bs[(it * 256 + (w << 6)) * 8]);
        }
        __syncthreads();

        bf16x8 af[4][2], bfr[4][2];
        #pragma unroll
        for (int m = 0; m < 4; ++m) {
            int r = wr * 64 + m * 16 + arow;
            af[m][0] = *(const bf16x8*)&As[r * 64 + ((kgrp ^ (r & 7)) * 8)];
            af[m][1] = *(const bf16x8*)&As[r * 64 + (((4 + kgrp) ^ (r & 7)) * 8)];
        }
        #pragma unroll
        for (int n = 0; n < 4; ++n) {
            int r = wc * 64 + n * 16 + arow;
            bfr[n][0] = *(const bf16x8*)&Bs[r * 64 + ((kgrp ^ (r & 7)) * 8)];
            bfr[n][1] = *(const bf16x8*)&Bs[r * 64 + (((4 + kgrp) ^ (r & 7)) * 8)];
        }
        #pragma unroll
        for (int m = 0; m < 4; ++m)
            #pragma unroll
            for (int n = 0; n < 4; ++n) {
                acc[m][n] = __builtin_amdgcn_mfma_f32_16x16x32_bf16(
                    af[m][0], bfr[n][0], acc[m][n], 0, 0, 0);
                acc[m][n] = __builtin_amdgcn_mfma_f32_16x16x32_bf16(
                    af[m][1], bfr[n][1], acc[m][n], 0, 0, 0);
            }
    }

    #pragma unroll
    for (int n = 0; n < 4; ++n) {
        int cg = c0t + wc * 64 + n * 16 + arow;
        float bi = bias[cg];
        #pragma unroll
        for (int m = 0; m < 4; ++m) {
            int tb = t0 + wr * 64 + m * 16 + kgrp * 4;
            int l0 = l_from_rn(tb >> 10, tb & 1023);
            float* p = out + (size_t)l0 * 512 + cg;
            #pragma unroll
            for (int i = 0; i < 4; ++i)
                p[(size_t)i * 512] = acc[m][n][i] + bi;
        }
    }
}

extern "C" void kernel_launch(void* const* d_in, const int* in_sizes, int n_in,
                              void* d_out, int out_size, void* d_ws, size_t ws_size,
                              hipStream_t stream) {
    const float* x      = (const float*)d_in[0];
    const float* qkv_w  = (const float*)d_in[1];
    const float* qkv_b  = (const float*)d_in[2];
    const float* proj_w = (const float*)d_in[3];
    const float* proj_b = (const float*)d_in[4];
    const float* epeg_w = (const float*)d_in[5];
    const float* epeg_b = (const float*)d_in[6];
    float* out = (float*)d_out;

    const size_t NTOK = (size_t)16384 * 512;
    unsigned short* xb    = (unsigned short*)d_ws;
    unsigned short* wqkv  = xb + NTOK;
    unsigned short* wproj = wqkv + (size_t)1536 * 512;
    unsigned short* qb    = wproj + (size_t)512 * 512;
    unsigned short* kb    = qb + NTOK;
    unsigned short* vtb   = kb + NTOK;
    unsigned short* ao    = vtb + NTOK;

    cast_x_kernel<<<4096, 256, 0, stream>>>(x, xb);
    cast_w_kernel<<<384, 256, 0, stream>>>(qkv_w, wqkv);
    cast_w_kernel<<<128, 256, 0, stream>>>(proj_w, wproj);
    {
        dim3 grid(12, 128);
        qkv_kernel<<<grid, 256, 0, stream>>>(xb, wqkv, qkv_b, qb, kb, vtb);
    }
    {
        dim3 grid(16, 8, 16);
        attn_kernel<<<grid, 256, 0, stream>>>(qb, kb, vtb, epeg_w, epeg_b, ao);
    }
    {
        dim3 grid(4, 128);
        proj_kernel<<<grid, 256, 0, stream>>>(ao, wproj, proj_b, out);
    }
}

// Round 5
// 169.976 us; speedup vs baseline: 9.6607x; 1.1513x over previous
//
#include <hip/hip_runtime.h>

// RegionAttention: bf16 MFMA everywhere; attention uses MFMA for QK, EPEG-conv
// (banded matmul), and PV; no-max softmax in exp2 domain; deferred row-sum.
// L=16384 -> 16 regions x 1024 tokens. HEADS=8, HD=64.
// q is stored PRE-SCALED by 0.125*log2(e) (folds attn scale + exp2 domain).

using bf16x8 = __attribute__((ext_vector_type(8))) short;
using f32x4  = __attribute__((ext_vector_type(4))) float;

__device__ __forceinline__ unsigned short f2bf(float f) {
    unsigned u = __float_as_uint(f);
    u += 0x7fff + ((u >> 16) & 1);
    return (unsigned short)(u >> 16);
}
__device__ __forceinline__ unsigned cvtpk(float lo, float hi) {
    unsigned r;
    asm("v_cvt_pk_bf16_f32 %0, %1, %2" : "=v"(r) : "v"(lo), "v"(hi));
    return r;
}
__device__ __forceinline__ void gload16(const void* g, void* l) {
    __builtin_amdgcn_global_load_lds(
        (const __attribute__((address_space(1))) void*)g,
        (__attribute__((address_space(3))) void*)l, 16, 0, 0);
}
__device__ __forceinline__ int l_from_rn(int region, int n) {
    int gi = region >> 2, gj = region & 3;
    int a = n >> 5, b = n & 31;
    return ((gi * 32 + a) << 7) + (gj << 5) + b;
}

// ---------------- cast kernels ----------------
__global__ __launch_bounds__(256) void cast_x_kernel(
    const float* __restrict__ x, unsigned short* __restrict__ xb)
{
    int tid = threadIdx.x;
    int t = blockIdx.x * 4 + (tid >> 6);
    int c8 = tid & 63;
    int l = l_from_rn(t >> 10, t & 1023);
    const float* src = x + (size_t)l * 512 + c8 * 8;
    float4 a = *(const float4*)src;
    float4 b = *(const float4*)(src + 4);
    bf16x8 o;
    o[0] = (short)f2bf(a.x); o[1] = (short)f2bf(a.y);
    o[2] = (short)f2bf(a.z); o[3] = (short)f2bf(a.w);
    o[4] = (short)f2bf(b.x); o[5] = (short)f2bf(b.y);
    o[6] = (short)f2bf(b.z); o[7] = (short)f2bf(b.w);
    *(bf16x8*)(xb + (size_t)t * 512 + c8 * 8) = o;
}

__global__ __launch_bounds__(256) void cast_w_kernel(
    const float* __restrict__ w, unsigned short* __restrict__ wb)
{
    int g = blockIdx.x * 256 + threadIdx.x;
    const float* src = w + (size_t)g * 8;
    float4 a = *(const float4*)src;
    float4 b = *(const float4*)(src + 4);
    bf16x8 o;
    o[0] = (short)f2bf(a.x); o[1] = (short)f2bf(a.y);
    o[2] = (short)f2bf(a.z); o[3] = (short)f2bf(a.w);
    o[4] = (short)f2bf(b.x); o[5] = (short)f2bf(b.y);
    o[6] = (short)f2bf(b.z); o[7] = (short)f2bf(b.w);
    *(bf16x8*)(wb + (size_t)g * 8) = o;
}

// ---------------- Kernel 1: QKV GEMM (bf16 MFMA) ----------------
__global__ __launch_bounds__(256) void qkv_kernel(
    const unsigned short* __restrict__ xb, const unsigned short* __restrict__ wb,
    const float* __restrict__ bias, unsigned short* __restrict__ qo,
    unsigned short* __restrict__ ko, unsigned short* __restrict__ vto)
{
    __shared__ __align__(16) unsigned short As[128 * 64];
    __shared__ __align__(16) unsigned short Bs[128 * 64];
    const int c0t = blockIdx.x * 128;
    const int t0 = blockIdx.y * 128;
    const int tid = threadIdx.x;
    const int lane = tid & 63, w = tid >> 6;
    const int arow = lane & 15, kgrp = lane >> 4;
    const int wr = w >> 1, wc = w & 1;

    f32x4 acc[4][4];
    #pragma unroll
    for (int m = 0; m < 4; ++m)
        #pragma unroll
        for (int n = 0; n < 4; ++n) {
            f32x4 z = {0.f, 0.f, 0.f, 0.f};
            acc[m][n] = z;
        }

    for (int k0 = 0; k0 < 512; k0 += 64) {
        __syncthreads();
        #pragma unroll
        for (int it = 0; it < 4; ++it) {
            int slot = it * 256 + tid;
            int row = slot >> 3, phys = slot & 7;
            int c8 = phys ^ (row & 7);
            gload16(xb + (size_t)(t0 + row) * 512 + k0 + c8 * 8,
                    &As[(it * 256 + (w << 6)) * 8]);
            gload16(wb + (size_t)(c0t + row) * 512 + k0 + c8 * 8,
                    &Bs[(it * 256 + (w << 6)) * 8]);
        }
        __syncthreads();

        bf16x8 af[4][2], bfr[4][2];
        #pragma unroll
        for (int m = 0; m < 4; ++m) {
            int r = wr * 64 + m * 16 + arow;
            af[m][0] = *(const bf16x8*)&As[r * 64 + ((kgrp ^ (r & 7)) * 8)];
            af[m][1] = *(const bf16x8*)&As[r * 64 + (((4 + kgrp) ^ (r & 7)) * 8)];
        }
        #pragma unroll
        for (int n = 0; n < 4; ++n) {
            int r = wc * 64 + n * 16 + arow;
            bfr[n][0] = *(const bf16x8*)&Bs[r * 64 + ((kgrp ^ (r & 7)) * 8)];
            bfr[n][1] = *(const bf16x8*)&Bs[r * 64 + (((4 + kgrp) ^ (r & 7)) * 8)];
        }
        #pragma unroll
        for (int m = 0; m < 4; ++m)
            #pragma unroll
            for (int n = 0; n < 4; ++n) {
                acc[m][n] = __builtin_amdgcn_mfma_f32_16x16x32_bf16(
                    af[m][0], bfr[n][0], acc[m][n], 0, 0, 0);
                acc[m][n] = __builtin_amdgcn_mfma_f32_16x16x32_bf16(
                    af[m][1], bfr[n][1], acc[m][n], 0, 0, 0);
            }
    }

    const int s = c0t >> 9;
    const int region = t0 >> 10;
    // q pre-scale: 0.125 (attn scale) * log2(e) (exp2-domain softmax)
    const float qs = (s == 0) ? 0.18033688f : 1.0f;
    #pragma unroll
    for (int n = 0; n < 4; ++n) {
        int cg = c0t + wc * 64 + n * 16 + arow;
        float bi = bias[cg];
        int h = (cg >> 6) & 7, d = cg & 63;
        if (s < 2) {
            unsigned short* dst = (s == 0) ? qo : ko;
            #pragma unroll
            for (int m = 0; m < 4; ++m) {
                int tb = t0 + wr * 64 + m * 16 + kgrp * 4;
                unsigned short* p =
                    dst + ((size_t)(region * 8 + h) * 1024 + (tb & 1023)) * 64 + d;
                #pragma unroll
                for (int i = 0; i < 4; ++i)
                    p[(size_t)i * 64] = f2bf((acc[m][n][i] + bi) * qs);
            }
        } else {
            #pragma unroll
            for (int m = 0; m < 4; ++m) {
                int tb = t0 + wr * 64 + m * 16 + kgrp * 4;
                ushort4 pk;
                pk.x = f2bf(acc[m][n][0] + bi);
                pk.y = f2bf(acc[m][n][1] + bi);
                pk.z = f2bf(acc[m][n][2] + bi);
                pk.w = f2bf(acc[m][n][3] + bi);
                *(ushort4*)(vto + (size_t)(region * 8 + h) * 65536 +
                            (size_t)d * 1024 + (tb & 1023)) = pk;
            }
        }
    }
}

// ---------------- Kernel 2: all-MFMA attention ----------------
// Per tile: QK MFMA -> S^T bf16 in LDS -> conv as banded MFMA (z rows lane-
// local) -> p=exp2(z) (no max-subtract; logits bounded) -> P bf16 -> PV MFMA.
__global__ __launch_bounds__(256) void attn_kernel(
    const unsigned short* __restrict__ qg, const unsigned short* __restrict__ kg,
    const unsigned short* __restrict__ vtg, const float* __restrict__ epw,
    const float* __restrict__ epb, unsigned short* __restrict__ ao)
{
    const int rb = blockIdx.x, head = blockIdx.y, region = blockIdx.z;
    const int rh = region * 8 + head;
    const unsigned short* qb = qg + (size_t)rh * 65536;
    const unsigned short* kb = kg + (size_t)rh * 65536;
    const unsigned short* vb = vtg + (size_t)rh * 65536;
    const int i0 = rb * 64;
    const int tid = threadIdx.x;
    const int lane = tid & 63, w = tid >> 6;
    const int arow = lane & 15, kgrp = lane >> 4;
    const int strow = w * 16 + arow;   // this thread's q-row (block-local)

    __shared__ __align__(16) unsigned short Ks[2][4096];
    __shared__ __align__(16) unsigned short VTs[2][4096];
    __shared__ __align__(16) unsigned short ST2[64 * 80]; // S^T [j][r], 160B rows
    __shared__ __align__(16) unsigned short Ps[4096];
    __shared__ float row_l[64];

    char* const st2b = (char*)ST2;
    // zero ST2 rows r in {0,1} (word 0) and {70..79} (bytes 140..159), once
    for (int idx = tid; idx < 64 * 6; idx += 256) {
        int j = idx / 6, sl = idx % 6;
        int off = (sl == 0) ? 0 : (136 + sl * 4);
        *(unsigned*)(st2b + j * 160 + off) = 0u;
    }

    // Q fragments (pre-scaled)
    bf16x8 qf0, qf1;
    {
        const unsigned short* p = qb + (size_t)(i0 + strow) * 64 + kgrp * 8;
        qf0 = *(const bf16x8*)p;
        qf1 = *(const bf16x8*)(p + 32);
    }
    // halo Q fragment: A-rows 0..3 = q rows {i0-2,i0-1,i0+64,i0+65}, rest zero
    bf16x8 qhf0, qhf1;
    #pragma unroll
    for (int e = 0; e < 8; ++e) { qhf0[e] = 0; qhf1[e] = 0; }
    {
        int gi = (arow < 2) ? (i0 - 2 + arow) : (i0 + 62 + arow);
        if (arow < 4 && gi >= 0 && gi < 1024) {
            const unsigned short* p = qb + (size_t)gi * 64 + kgrp * 8;
            qhf0 = *(const bf16x8*)p;
            qhf1 = *(const bf16x8*)(p + 32);
        }
    }

    // Band B-fragment (constant): B[k][n=arow] = cwt[k-n-2], k = kgrp*8+e
    bf16x8 bandf;
    {
        float cwt[5];
        #pragma unroll
        for (int t = 0; t < 5; ++t) cwt[t] = epw[head * 5 + t];
        cwt[2] += 1.0f;   // identity (direct S) term
        #pragma unroll
        for (int e = 0; e < 8; ++e) {
            int k = kgrp * 8 + e;
            int c = k - arow - 2;
            float v = 0.f;
            v = (c == 0) ? cwt[0] : v;
            v = (c == 1) ? cwt[1] : v;
            v = (c == 2) ? cwt[2] : v;
            v = (c == 3) ? cwt[3] : v;
            v = (c == 4) ? cwt[4] : v;
            bandf[e] = (short)f2bf(v);
        }
    }

    f32x4 oacc[4];
    #pragma unroll
    for (int dt = 0; dt < 4; ++dt) {
        f32x4 z = {0.f, 0.f, 0.f, 0.f};
        oacc[dt] = z;
    }
    float l_part = 0.f;

    auto stage = [&](int jt, int buf) {
        const int j0 = jt * 64;
        #pragma unroll
        for (int it = 0; it < 2; ++it) {
            int q_ = (it * 4 + w) * 64 + lane;
            int row = q_ >> 3, phys = q_ & 7, c8 = phys ^ (row & 7);
            gload16(kb + (size_t)(j0 + row) * 64 + c8 * 8,
                    &Ks[buf][(it * 4 + w) * 512]);
            gload16(vb + (size_t)row * 1024 + j0 + c8 * 8,
                    &VTs[buf][(it * 4 + w) * 512]);
        }
    };

    stage(0, 0);

    for (int jt = 0; jt < 16; ++jt) {
        const int cur = jt & 1;
        __syncthreads();   // staged tile landed; ST2/Ps reads of prev tile done
        if (jt < 15) stage(jt + 1, cur ^ 1);

        const unsigned short* Kc = &Ks[cur][0];
        // QK -> S^T bf16 (rows r = q+4); halo rows r={2,3,68,69} on ct==w
        #pragma unroll
        for (int ct = 0; ct < 4; ++ct) {
            f32x4 sacc = {0.f, 0.f, 0.f, 0.f};
            int krow = ct * 16 + arow;
            bf16x8 kf0 = *(const bf16x8*)&Kc[krow * 64 + ((kgrp ^ (krow & 7)) * 8)];
            bf16x8 kf1 = *(const bf16x8*)&Kc[krow * 64 + (((4 + kgrp) ^ (krow & 7)) * 8)];
            sacc = __builtin_amdgcn_mfma_f32_16x16x32_bf16(qf0, kf0, sacc, 0, 0, 0);
            sacc = __builtin_amdgcn_mfma_f32_16x16x32_bf16(qf1, kf1, sacc, 0, 0, 0);
            uint2 uu;
            uu.x = cvtpk(sacc[0], sacc[1]);
            uu.y = cvtpk(sacc[2], sacc[3]);
            *(uint2*)(st2b + krow * 160 + 8 + w * 32 + kgrp * 8) = uu;
            if (ct == w) {
                f32x4 hacc = {0.f, 0.f, 0.f, 0.f};
                hacc = __builtin_amdgcn_mfma_f32_16x16x32_bf16(qhf0, kf0, hacc, 0, 0, 0);
                hacc = __builtin_amdgcn_mfma_f32_16x16x32_bf16(qhf1, kf1, hacc, 0, 0, 0);
                if (kgrp == 0) {
                    *(unsigned*)(st2b + krow * 160 + 4)   = cvtpk(hacc[0], hacc[1]);
                    *(unsigned*)(st2b + krow * 160 + 136) = cvtpk(hacc[2], hacc[3]);
                }
            }
        }
        // S^T visible to all waves; prefetch stays in flight (no vmcnt drain)
        asm volatile("s_waitcnt lgkmcnt(0)\n\ts_barrier" ::: "memory");

        // conv via banded MFMA: D^T[j][i], i = arow lane-local; then exp2 + pack
        #pragma unroll
        for (int ct = 0; ct < 4; ++ct) {
            bf16x8 saf = *(const bf16x8*)(st2b + (ct * 16 + arow) * 160 +
                                          w * 32 + kgrp * 16);
            f32x4 zacc = {0.f, 0.f, 0.f, 0.f};
            zacc = __builtin_amdgcn_mfma_f32_16x16x32_bf16(saf, bandf, zacc, 0, 0, 0);
            float p0 = exp2f(zacc[0]), p1 = exp2f(zacc[1]);
            float p2 = exp2f(zacc[2]), p3 = exp2f(zacc[3]);
            l_part += (p0 + p1) + (p2 + p3);
            uint2 uu;
            uu.x = cvtpk(p0, p1);
            uu.y = cvtpk(p2, p3);
            *(uint2*)((char*)Ps + strow * 128 +
                      (((2 * ct + (kgrp >> 1)) ^ (arow & 7)) << 4) +
                      ((kgrp & 1) << 3)) = uu;
        }
        // PV (wave-local P reads; DS ops in-order per wave)
        {
            const unsigned short* Vc = &VTs[cur][0];
            const char* psb = (const char*)Ps;
            bf16x8 pf0 = *(const bf16x8*)(psb + strow * 128 +
                                          ((kgrp ^ (arow & 7)) << 4));
            bf16x8 pf1 = *(const bf16x8*)(psb + strow * 128 +
                                          (((4 + kgrp) ^ (arow & 7)) << 4));
            #pragma unroll
            for (int dt = 0; dt < 4; ++dt) {
                int drow = dt * 16 + arow;
                bf16x8 vf0 = *(const bf16x8*)&Vc[drow * 64 + ((kgrp ^ (drow & 7)) * 8)];
                bf16x8 vf1 = *(const bf16x8*)&Vc[drow * 64 + (((4 + kgrp) ^ (drow & 7)) * 8)];
                oacc[dt] = __builtin_amdgcn_mfma_f32_16x16x32_bf16(pf0, vf0, oacc[dt], 0, 0, 0);
                oacc[dt] = __builtin_amdgcn_mfma_f32_16x16x32_bf16(pf1, vf1, oacc[dt], 0, 0, 0);
            }
        }
    }

    // finalize row sums (deferred): reduce across the 4 kgrp lane-groups
    l_part += __shfl_xor(l_part, 16);
    l_part += __shfl_xor(l_part, 32);
    if (kgrp == 0) row_l[strow] = l_part;
    __syncthreads();
    float inv[4];
    #pragma unroll
    for (int i = 0; i < 4; ++i) inv[i] = 1.f / row_l[w * 16 + kgrp * 4 + i];
    #pragma unroll
    for (int dt = 0; dt < 4; ++dt) {
        #pragma unroll
        for (int i = 0; i < 4; ++i) {
            size_t t = (size_t)region * 1024 + i0 + w * 16 + kgrp * 4 + i;
            ao[t * 512 + head * 64 + dt * 16 + arow] = f2bf(oacc[dt][i] * inv[i]);
        }
    }
}

// ---------------- Kernel 3: proj GEMM (bf16 MFMA, fp32 out, un-permute) -------------
__global__ __launch_bounds__(256) void proj_kernel(
    const unsigned short* __restrict__ ab, const unsigned short* __restrict__ wb,
    const float* __restrict__ bias, float* __restrict__ out)
{
    __shared__ __align__(16) unsigned short As[128 * 64];
    __shared__ __align__(16) unsigned short Bs[128 * 64];
    const int c0t = blockIdx.x * 128;
    const int t0 = blockIdx.y * 128;
    const int tid = threadIdx.x;
    const int lane = tid & 63, w = tid >> 6;
    const int arow = lane & 15, kgrp = lane >> 4;
    const int wr = w >> 1, wc = w & 1;

    f32x4 acc[4][4];
    #pragma unroll
    for (int m = 0; m < 4; ++m)
        #pragma unroll
        for (int n = 0; n < 4; ++n) {
            f32x4 z = {0.f, 0.f, 0.f, 0.f};
            acc[m][n] = z;
        }

    for (int k0 = 0; k0 < 512; k0 += 64) {
        __syncthreads();
        #pragma unroll
        for (int it = 0; it < 4; ++it) {
            int slot = it * 256 + tid;
            int row = slot >> 3, phys = slot & 7;
            int c8 = phys ^ (row & 7);
            gload16(ab + (size_t)(t0 + row) * 512 + k0 + c8 * 8,
                    &As[(it * 256 + (w << 6)) * 8]);
            gload16(wb + (size_t)(c0t + row) * 512 + k0 + c8 * 8,
                    &Bs[(it * 256 + (w << 6)) * 8]);
        }
        __syncthreads();

        bf16x8 af[4][2], bfr[4][2];
        #pragma unroll
        for (int m = 0; m < 4; ++m) {
            int r = wr * 64 + m * 16 + arow;
            af[m][0] = *(const bf16x8*)&As[r * 64 + ((kgrp ^ (r & 7)) * 8)];
            af[m][1] = *(const bf16x8*)&As[r * 64 + (((4 + kgrp) ^ (r & 7)) * 8)];
        }
        #pragma unroll
        for (int n = 0; n < 4; ++n) {
            int r = wc * 64 + n * 16 + arow;
            bfr[n][0] = *(const bf16x8*)&Bs[r * 64 + ((kgrp ^ (r & 7)) * 8)];
            bfr[n][1] = *(const bf16x8*)&Bs[r * 64 + (((4 + kgrp) ^ (r & 7)) * 8)];
        }
        #pragma unroll
        for (int m = 0; m < 4; ++m)
            #pragma unroll
            for (int n = 0; n < 4; ++n) {
                acc[m][n] = __builtin_amdgcn_mfma_f32_16x16x32_bf16(
                    af[m][0], bfr[n][0], acc[m][n], 0, 0, 0);
                acc[m][n] = __builtin_amdgcn_mfma_f32_16x16x32_bf16(
                    af[m][1], bfr[n][1], acc[m][n], 0, 0, 0);
            }
    }

    #pragma unroll
    for (int n = 0; n < 4; ++n) {
        int cg = c0t + wc * 64 + n * 16 + arow;
        float bi = bias[cg];
        #pragma unroll
        for (int m = 0; m < 4; ++m) {
            int tb = t0 + wr * 64 + m * 16 + kgrp * 4;
            int l0 = l_from_rn(tb >> 10, tb & 1023);
            float* p = out + (size_t)l0 * 512 + cg;
            #pragma unroll
            for (int i = 0; i < 4; ++i)
                p[(size_t)i * 512] = acc[m][n][i] + bi;
        }
    }
}

extern "C" void kernel_launch(void* const* d_in, const int* in_sizes, int n_in,
                              void* d_out, int out_size, void* d_ws, size_t ws_size,
                              hipStream_t stream) {
    const float* x      = (const float*)d_in[0];
    const float* qkv_w  = (const float*)d_in[1];
    const float* qkv_b  = (const float*)d_in[2];
    const float* proj_w = (const float*)d_in[3];
    const float* proj_b = (const float*)d_in[4];
    const float* epeg_w = (const float*)d_in[5];
    const float* epeg_b = (const float*)d_in[6];
    float* out = (float*)d_out;

    const size_t NTOK = (size_t)16384 * 512;
    unsigned short* xb    = (unsigned short*)d_ws;
    unsigned short* wqkv  = xb + NTOK;
    unsigned short* wproj = wqkv + (size_t)1536 * 512;
    unsigned short* qb    = wproj + (size_t)512 * 512;
    unsigned short* kb    = qb + NTOK;
    unsigned short* vtb   = kb + NTOK;
    unsigned short* ao    = vtb + NTOK;

    cast_x_kernel<<<4096, 256, 0, stream>>>(x, xb);
    cast_w_kernel<<<384, 256, 0, stream>>>(qkv_w, wqkv);
    cast_w_kernel<<<128, 256, 0, stream>>>(proj_w, wproj);
    {
        dim3 grid(12, 128);
        qkv_kernel<<<grid, 256, 0, stream>>>(xb, wqkv, qkv_b, qb, kb, vtb);
    }
    {
        dim3 grid(16, 8, 16);
        attn_kernel<<<grid, 256, 0, stream>>>(qb, kb, vtb, epeg_w, epeg_b, ao);
    }
    {
        dim3 grid(4, 128);
        proj_kernel<<<grid, 256, 0, stream>>>(ao, wproj, proj_b, out);
    }
}